// Round 1
// 1009.600 us; speedup vs baseline: 1.0146x; 1.0146x over previous
//
#include <hip/hip_runtime.h>

// GroupDenseFull: out[b, t*8+v] = sum_s ( sum_w x[b, s*8+w] * kseq[s,w,v] ) * kf[s,t]
// B=131072, C=1024, S=128, W=8.
// Stage 1 in fp32 VALU (2.1 GFLOP), stage 2 via bf16 MFMA 16x16x32 (34.4 GFLOP).
// Memory-bound target: 1.07 GiB HBM traffic -> ~170 us floor.
//
// R1: latency-hiding rework. Stage 1 loads are batched per s-half (8 x-b128 +
// 8 kseq-b128 in flight at once, ~12 KB/wave) instead of 2-at-a-time. The
// stage-2 K dimension is permuted (p = 2*sg + half) so the proven conflict-free
// packed-b32 LDS write path is preserved; the same permutation is baked into
// kfT by the prep kernel (MFMA k-order is irrelevant as long as A and B agree).

#define NB 131072
#define NS 128
#define NW 8
#define NC 1024
#define TB 16          // rows per block
#define YROW 136       // padded LDS row stride (bf16 elems) per (v,m): 128 + 8
#define YV (16 * YROW) // 2176 bf16 per v-plane

typedef __attribute__((ext_vector_type(8))) short short8;   // 8 bf16 = 4 VGPRs
typedef __attribute__((ext_vector_type(4))) float float4v;

__device__ __forceinline__ unsigned short f2bf(float f) {
    union { float f; unsigned int u; } c; c.f = f;
    unsigned int u = c.u;
    // round-to-nearest-even
    unsigned int r = (u + 0x7FFFu + ((u >> 16) & 1u)) >> 16;
    return (unsigned short)r;
}

// Transpose + bf16-convert kernel_full into d_ws, with the stage-2 k-permutation
// baked in: position p holds original s = (p>>1) + (p&1)*64.
// kfT[t*128 + p] = bf16(kf[s(p)*128 + t])
__global__ __launch_bounds__(256) void gdf_prep_kfT(const float* __restrict__ kf,
                                                    unsigned short* __restrict__ kfT) {
    int tid = blockIdx.x * 256 + threadIdx.x;   // 0..16383
    int p = tid >> 7;                 // k-position 0..127
    int t = tid & 127;
    int s = (p >> 1) + (p & 1) * 64;  // original s stored at position p
    kfT[t * 128 + p] = f2bf(kf[s * 128 + t]);
}

__global__ __launch_bounds__(512, 4) void gdf_main(const float* __restrict__ x,
                                                   const float* __restrict__ kseq,
                                                   const unsigned short* __restrict__ kfT,
                                                   float* __restrict__ out) {
    __shared__ unsigned short ylds[8 * YV];  // 34816 B: y tile, bf16, [v][m][p] padded

    const int tid = threadIdx.x;
    const int b0 = blockIdx.x * TB;

    const int lane = tid & 63;
    const int wv   = tid >> 6;       // 0..7 -> t-tile
    const int colm = lane & 15;      // n (B/t) and m (A row) index within tile
    const int quad = lane >> 4;      // 0..3
    const int t0   = wv * 16;

    // ---------------- pass 1: y[m][s][v] tile in fp32, store bf16 to LDS ----
    // thread -> (vg, mg, sg): 2 * 4 * 64 = 512
    const int sg = tid & 63;          // s in {sg, sg+64}  (two halves)
    const int mg = (tid >> 6) & 3;    // m in [mg*4, mg*4+4)
    const int vg = tid >> 8;          // v in [vg*4, vg*4+4)

    float acc[4][2][4];               // [ml][half][vl]
#pragma unroll
    for (int ml = 0; ml < 4; ++ml)
#pragma unroll
        for (int h = 0; h < 2; ++h)
#pragma unroll
            for (int vl = 0; vl < 4; ++vl) acc[ml][h][vl] = 0.0f;

#pragma unroll
    for (int h = 0; h < 2; ++h) {
        const int s = sg + h * 64;

        // ---- batched load burst: 8 x-b128 (HBM) + 8 kseq-b128 (L2-hot) ----
        float4v xr[4][2];
#pragma unroll
        for (int ml = 0; ml < 4; ++ml) {
            const float* xp = x + (size_t)(b0 + mg * 4 + ml) * NC + s * 8;
            xr[ml][0] = *(const float4v*)(xp);
            xr[ml][1] = *(const float4v*)(xp + 4);
        }
        float4v kq[8];
#pragma unroll
        for (int w = 0; w < 8; ++w)
            kq[w] = *(const float4v*)(kseq + s * 64 + w * 8 + vg * 4);

        // ---- compute: 128 FMAs per half ----
#pragma unroll
        for (int ml = 0; ml < 4; ++ml) {
#pragma unroll
            for (int w = 0; w < 4; ++w) {
#pragma unroll
                for (int vl = 0; vl < 4; ++vl) {
                    acc[ml][h][vl] = fmaf(xr[ml][0][w], kq[w][vl],     acc[ml][h][vl]);
                    acc[ml][h][vl] = fmaf(xr[ml][1][w], kq[w + 4][vl], acc[ml][h][vl]);
                }
            }
        }
    }

    // write bf16 pairs (half0, half1) -> position p = 2*sg (+1): conflict-free
    // stride-1 b32 writes, identical pattern to the proven kernel.
#pragma unroll
    for (int vl = 0; vl < 4; ++vl) {
#pragma unroll
        for (int ml = 0; ml < 4; ++ml) {
            const int v = vg * 4 + vl;
            const int m = mg * 4 + ml;
            unsigned int pk = (unsigned int)f2bf(acc[ml][0][vl]) |
                              ((unsigned int)f2bf(acc[ml][1][vl]) << 16);
            *(unsigned int*)&ylds[v * YV + m * YROW + sg * 2] = pk;
        }
    }

    // bfrag loads here (not at kernel top): frees 16 VGPRs during the stage-1
    // register peak; L2 latency hides under the barrier drain.
    short8 bfrag[4];
#pragma unroll
    for (int q = 0; q < 4; ++q)
        bfrag[q] = *(const short8*)(kfT + (t0 + colm) * 128 + q * 32 + quad * 8);

    __syncthreads();

    // ---------------- pass 2: z_v = Y_v (16x128) * kf (128x128), MFMA -------
    float4v accv[8];
#pragma unroll
    for (int v = 0; v < 8; ++v) accv[v] = (float4v){0.f, 0.f, 0.f, 0.f};

#pragma unroll
    for (int v = 0; v < 8; ++v) {
        const unsigned short* ap = ylds + v * YV + colm * YROW + quad * 8;
#pragma unroll
        for (int q = 0; q < 4; ++q) {
            short8 af = *(const short8*)(ap + q * 32);
            accv[v] = __builtin_amdgcn_mfma_f32_16x16x32_bf16(af, bfrag[q], accv[v], 0, 0, 0);
        }
    }

    // epilogue: transpose v into contiguous 32B per (row,t) -> coalesced float4 stores
#pragma unroll
    for (int r = 0; r < 4; ++r) {
        float4v lo = {accv[0][r], accv[1][r], accv[2][r], accv[3][r]};
        float4v hi = {accv[4][r], accv[5][r], accv[6][r], accv[7][r]};
        float* p = out + (size_t)(b0 + quad * 4 + r) * NC + (t0 + colm) * 8;
        *(float4v*)p       = lo;
        *(float4v*)(p + 4) = hi;
    }
}

extern "C" void kernel_launch(void* const* d_in, const int* in_sizes, int n_in,
                              void* d_out, int out_size, void* d_ws, size_t ws_size,
                              hipStream_t stream) {
    const float* x    = (const float*)d_in[0];  // (131072, 1024)
    const float* kseq = (const float*)d_in[1];  // (128, 8, 8)
    const float* kf   = (const float*)d_in[2];  // (128, 128)
    float* out = (float*)d_out;
    unsigned short* kfT = (unsigned short*)d_ws;  // needs 32 KiB

    gdf_prep_kfT<<<64, 256, 0, stream>>>(kf, kfT);
    gdf_main<<<NB / TB, 512, 0, stream>>>(x, kseq, kfT, out);
}